// Round 16
// baseline (352.787 us; speedup 1.0000x reference)
//
#include <hip/hip_runtime.h>
#include <hip/hip_bf16.h>
#include <math.h>

#define BB 16
#define NN_ 1024
#define TT 12

typedef __attribute__((ext_vector_type(8))) short bf16x8;
typedef __attribute__((ext_vector_type(4))) float f32x4;

// ---------------- workspace layout (float units) ----------------
static const size_t ACC_OFF    = 0;          // 16
static const size_t COLSUM_OFF = 16;         // B*N = 16384
static const size_t TAT_OFF    = 16400;      // B*T*T = 2304
static const size_t LHST_OFF   = 18704;      // B*N*T = 196608
static const size_t RHS2_OFF   = 215312;     // B*T*N = 196608
static const size_t VSB_OFF    = 411920;     // N*N bf16 = 524288 floats
static const size_t SIG2B_OFF  = 936208;     // B*N*N bf16 = 8388608 floats
static const size_t CHEBB_OFF  = 9324816;    // 3*N*N bf16 = 1572864 floats
static const size_t EXPS_OFF   = 10897680;   // B*N*N bf16 = 8388608 floats
static const size_t RHSC_OFF   = 19286288;   // 2 x B*K*N*F*T fp32 (z-partials)
static const size_t WTG_OFF    = 26364176;   // 192*64 bf16 = 6144 floats
static const size_t PART_OFF   = 26370320;   // 2048 floats
// total ~26372368 floats = ~105 MB

#define RHSC_SZ 1769472

__device__ __forceinline__ float wave_reduce_sum(float v) {
    #pragma unroll
    for (int off = 32; off > 0; off >>= 1) v += __shfl_down(v, off);
    return v;
}

__device__ __forceinline__ unsigned short f2b(float f) {
    __hip_bfloat16 h = __float2bfloat16(f);
    return *(unsigned short*)&h;
}
__device__ __forceinline__ float b2f(unsigned short u) {
    return __uint_as_float(((unsigned int)u) << 16);
}

// ---------------- fused prologue: init | cvtw | temporal | cvt(Vs) | cvt(cheb) ----
// 512 threads/block. Temporal branch now has 2x thread parallelism (2 n/thread).
// Branches are block-uniform (barriers legal).
__global__ __launch_bounds__(512) void k_pre(
    float* __restrict__ ws,
    const float* __restrict__ tcw, unsigned short* __restrict__ WtG,
    const float* __restrict__ x, const float* __restrict__ U1,
    const float* __restrict__ U2, const float* __restrict__ U3,
    const float* __restrict__ be, const float* __restrict__ Ve,
    float* __restrict__ tat,
    const float* __restrict__ Vs, unsigned short* __restrict__ Vsb,
    const float* __restrict__ cheb, unsigned short* __restrict__ chebb)
{
    const int blk = blockIdx.x;
    const int tid = threadIdx.x;
    if (blk < 33) {
        // ---- init: zero acc + colsum (16400 floats) ----
        const int i = blk * 512 + tid;
        if (i < 16400) ws[i] = 0.f;
    } else if (blk == 33) {
        // ---- tcw -> WtG[d*64+c][cp] bf16 ----
        for (int j = tid; j < 12288; j += 512) {
            const int row = j >> 6;
            const int cp  = j & 63;
            const int d   = row >> 6;
            const int c   = row & 63;
            WtG[j] = f2b(tcw[c * 192 + 3 * cp + d]);
        }
    } else if (blk < 50) {
        // ---- temporal attention -> tat (B,T,T); 512 threads, 2 n/thread ----
        const int b = blk - 34;
        const int wid = tid >> 6, lane = tid & 63;
        float lA[36], lM[36];
        #pragma unroll
        for (int i = 0; i < 36; ++i) { lA[i] = 0.f; lM[i] = 0.f; }
        const float u30 = U3[0], u31 = U3[1], u32 = U3[2];
        for (int n = tid; n < NN_; n += 512) {
            const float* xp = x + ((size_t)b * NN_ + n) * 36;
            float xr[36];
            #pragma unroll
            for (int i = 0; i < 9; ++i) *(float4*)&xr[i*4] = *(const float4*)(xp + i*4);
            const float u1  = U1[n];
            const float u20 = U2[n], u21 = U2[NN_ + n], u22 = U2[2*NN_ + n];
            #pragma unroll
            for (int t = 0; t < 12; ++t) {
                float ru = xr[t]*u30 + xr[12+t]*u31 + xr[24+t]*u32;
                lM[t]    += u20 * ru;
                lM[12+t] += u21 * ru;
                lM[24+t] += u22 * ru;
                lA[t]    += xr[t]    * u1;
                lA[12+t] += xr[12+t] * u1;
                lA[24+t] += xr[24+t] * u1;
            }
        }
        __shared__ float pA[8][36], pM[8][36];
        __shared__ float tA[36], tM[36], sgs[144], es[144], cmax[12], csum[12];
        #pragma unroll
        for (int i = 0; i < 36; ++i) {
            float v = wave_reduce_sum(lA[i]);
            if (lane == 0) pA[wid][i] = v;
            float w = wave_reduce_sum(lM[i]);
            if (lane == 0) pM[wid][i] = w;
        }
        __syncthreads();
        if (tid < 36) {
            float s = 0.f;
            #pragma unroll
            for (int w = 0; w < 8; ++w) s += pA[w][tid];
            tA[tid] = s;
        } else if (tid < 72) {
            const int i = tid - 36;
            float s = 0.f;
            #pragma unroll
            for (int w = 0; w < 8; ++w) s += pM[w][i];
            tM[i] = s;
        }
        __syncthreads();
        if (tid < 144) {
            int t = tid / 12, u = tid % 12;
            float p = tA[t]*tM[u] + tA[12+t]*tM[12+u] + tA[24+t]*tM[24+u];
            p += be[tid];
            sgs[tid] = 1.f / (1.f + expf(-p));
        }
        __syncthreads();
        if (tid < 144) {
            int i = tid / 12, j = tid % 12;
            float e = 0.f;
            #pragma unroll
            for (int k = 0; k < 12; ++k) e += sgs[i*12 + k] * Ve[j*12 + k];
            es[tid] = e;
        }
        __syncthreads();
        if (tid < 12) {
            int j = tid;
            float m = -1e30f;
            for (int i = 0; i < 12; ++i) m = fmaxf(m, es[i*12 + j]);
            float sx = 0.f;
            for (int i = 0; i < 12; ++i) sx += expf(es[i*12 + j] - m);
            cmax[j] = m; csum[j] = sx;
        }
        __syncthreads();
        if (tid < 144) {
            int j = tid % 12;
            tat[(size_t)b*144 + tid] = expf(es[tid] - cmax[j]) / csum[j];
        }
    } else if (blk < 562) {
        // ---- Vs fp32 -> bf16 (262144 float4) ----
        const int i = (blk - 50) * 512 + tid;
        float4 v = ((const float4*)Vs)[i];
        ushort4 o;
        o.x = f2b(v.x); o.y = f2b(v.y); o.z = f2b(v.z); o.w = f2b(v.w);
        ((ushort4*)Vsb)[i] = o;
    } else {
        // ---- cheb fp32 -> bf16 (786432 float4) ----
        const int i = (blk - 562) * 512 + tid;
        float4 v = ((const float4*)cheb)[i];
        ushort4 o;
        o.x = f2b(v.x); o.y = f2b(v.y); o.z = f2b(v.z); o.w = f2b(v.w);
        ((ushort4*)chebb)[i] = o;
    }
}

// ---------------- x_tat projections -> lhsT (B,N,T), rhs2 (B,T,N) ----------------
__global__ __launch_bounds__(256) void k_xtat(
    const float* __restrict__ x, const float* __restrict__ tat,
    const float* __restrict__ W1, const float* __restrict__ W2,
    const float* __restrict__ W3,
    float* __restrict__ lhsT, float* __restrict__ rhs2)
{
    const int id = blockIdx.x * 256 + threadIdx.x;
    const int b = id >> 10, n = id & 1023;
    const float* xp = x + (size_t)id * 36;
    float xr[36];
    #pragma unroll
    for (int i = 0; i < 9; ++i) *(float4*)&xr[i*4] = *(const float4*)(xp + i*4);
    const float* tp = tat + (size_t)b * 144;
    float xt[36];
    #pragma unroll
    for (int f = 0; f < 3; ++f)
        #pragma unroll
        for (int u = 0; u < 12; ++u) {
            float s = 0.f;
            #pragma unroll
            for (int t = 0; t < 12; ++t) s += xr[f*12 + t] * tp[t*12 + u];
            xt[f*12 + u] = s;
        }
    float lA0 = 0.f, lA1 = 0.f, lA2 = 0.f;
    #pragma unroll
    for (int t = 0; t < 12; ++t) {
        float w = W1[t];
        lA0 += xt[t]*w; lA1 += xt[12+t]*w; lA2 += xt[24+t]*w;
    }
    #pragma unroll
    for (int t2 = 0; t2 < 12; ++t2)
        lhsT[(size_t)id*12 + t2] = lA0*W2[t2] + lA1*W2[12+t2] + lA2*W2[24+t2];
    const float w30 = W3[0], w31 = W3[1], w32 = W3[2];
    #pragma unroll
    for (int u = 0; u < 12; ++u)
        rhs2[((size_t)b*12 + u)*NN_ + n] = xt[u]*w30 + xt[12+u]*w31 + xt[24+u]*w32;
}

// ---------------- sig2 (B,N,N) -> bf16, rhs2-in-registers ----------------
__global__ __launch_bounds__(256) void k_sig2(
    const float* __restrict__ lhsT, const float* __restrict__ rhs2,
    const float* __restrict__ bs, unsigned short* __restrict__ sig2b)
{
    const int nt = blockIdx.x & 63;       // n-tile (16 rows)
    const int mt = blockIdx.x >> 6;       // m-tile (64 cols)
    const int mq = threadIdx.x & 15;
    const int b  = threadIdx.x >> 4;
    const int m4 = mt * 64 + mq * 4;
    const int n0 = nt * 16;
    float4 r[12];
    #pragma unroll
    for (int t = 0; t < 12; ++t)
        r[t] = *(const float4*)(rhs2 + ((size_t)b * 12 + t) * NN_ + m4);
    const float* lb = lhsT + ((size_t)b * NN_ + n0) * 12;
    #pragma unroll 4
    for (int ni = 0; ni < 16; ++ni) {
        const float* lp = lb + ni * 12;
        float l[12];
        *(float4*)&l[0] = *(const float4*)(lp);
        *(float4*)&l[4] = *(const float4*)(lp + 4);
        *(float4*)&l[8] = *(const float4*)(lp + 8);
        float4 z = *(const float4*)(bs + (size_t)(n0 + ni) * NN_ + m4);
        #pragma unroll
        for (int t = 0; t < 12; ++t) {
            z.x += l[t] * r[t].x; z.y += l[t] * r[t].y;
            z.z += l[t] * r[t].z; z.w += l[t] * r[t].w;
        }
        ushort4 o;
        o.x = f2b(1.f / (1.f + __expf(-z.x)));
        o.y = f2b(1.f / (1.f + __expf(-z.y)));
        o.z = f2b(1.f / (1.f + __expf(-z.z)));
        o.w = f2b(1.f / (1.f + __expf(-z.w)));
        *(ushort4*)(sig2b + ((size_t)b * NN_ + n0 + ni) * NN_ + m4) = o;
    }
}

// ---------------- S = sig2 @ Vs^T, fused exp + colsum; store expS bf16 ----------------
// 2-phase K-loop, 128x128 tile (R11: keep 92 VGPR/32KB for TLP). Batch-split via
// boff: grid z = batch count; gridDim.z-parametric bijective XCD swizzle (each
// XCD owns contiguous tile chunk; 8 j-tiles sharing an A-panel stay adjacent).
__global__ __launch_bounds__(256) void k_gemm_s_mfma(
    const short* __restrict__ A, const short* __restrict__ Bm,
    unsigned short* __restrict__ E, float* __restrict__ colsum, int boff)
{
    __shared__ __align__(16) short smemU[16384];   // 32 KB: two 16 KB buffers
    const int lid = blockIdx.x + 8 * (blockIdx.y + 8 * blockIdx.z);
    const int tile = (lid & 7) * (8 * (int)gridDim.z) + (lid >> 3);
    const int j0 = (tile & 7) * 128;
    const int i0 = ((tile >> 3) & 7) * 128;
    const int b  = boff + (tile >> 6);
    const int tid = threadIdx.x;
    const int wid = tid >> 6;
    const int lane = tid & 63;
    const int wr = wid & 1, wc = wid >> 1;
    const short* Ab = A + (size_t)b * NN_ * NN_;

    f32x4 acc[4][4];
    const f32x4 z4 = {0.f, 0.f, 0.f, 0.f};
    #pragma unroll
    for (int m = 0; m < 4; ++m)
        #pragma unroll
        for (int n = 0; n < 4; ++n) acc[m][n] = z4;

    const int srow = lane >> 2;
    const int schk = lane & 3;
    const int fr = lane & 15;
    const int kb = (lane >> 4) * 8;

    auto STAGE = [&](int bufofs, int k0) {
        #pragma unroll
        for (int q = 0; q < 2; ++q) {
            const int rb = (wid * 2 + q) * 16;
            const short* srcA = Ab + (size_t)(i0 + rb + srow) * NN_ + k0 + schk * 8;
            const short* srcB = Bm + (size_t)(j0 + rb + srow) * NN_ + k0 + schk * 8;
            __builtin_amdgcn_global_load_lds(
                (const __attribute__((address_space(1))) unsigned int*)srcA,
                (__attribute__((address_space(3))) unsigned int*)(smemU + bufofs + rb * 32), 16, 0, 0);
            __builtin_amdgcn_global_load_lds(
                (const __attribute__((address_space(1))) unsigned int*)srcB,
                (__attribute__((address_space(3))) unsigned int*)(smemU + bufofs + 4096 + rb * 32), 16, 0, 0);
        }
    };

    // prologue: stage tile 0 into buffer 0
    STAGE(0, 0);
    __syncthreads();

    int cur = 0;
    for (int k0 = 0; k0 < NN_; k0 += 32) {
        // issue next tile's loads FIRST (into the other buffer; no reader this step)
        if (k0 + 32 < NN_) STAGE((cur ^ 1) * 8192, k0 + 32);
        const short* As = smemU + cur * 8192;
        const short* Bs = smemU + cur * 8192 + 4096;
        bf16x8 aF[4], bF[4];
        #pragma unroll
        for (int m = 0; m < 4; ++m)
            aF[m] = *(const bf16x8*)(As + (wr*64 + m*16 + fr) * 32 + kb);
        #pragma unroll
        for (int n = 0; n < 4; ++n)
            bF[n] = *(const bf16x8*)(Bs + (wc*64 + n*16 + fr) * 32 + kb);
        __builtin_amdgcn_s_setprio(1);
        #pragma unroll
        for (int m = 0; m < 4; ++m)
            #pragma unroll
            for (int n = 0; n < 4; ++n)
                acc[m][n] = __builtin_amdgcn_mfma_f32_16x16x32_bf16(aF[m], bF[n], acc[m][n], 0, 0, 0);
        __builtin_amdgcn_s_setprio(0);
        __syncthreads();   // drains vmcnt(0): next tile landed; all reads of cur done
        cur ^= 1;
    }
    // ---- epilogue: exp(acc) -> LDS (bf16, aliases buffers) -> dwordx4 flush ----
    unsigned short* Es = (unsigned short*)smemU;   // rows of stride 136 ushorts (272 B)
    unsigned short* Ep = E + (size_t)b * NN_ * NN_;
    const int cn = lane & 15;
    const int r0 = (lane >> 4) * 4;
    float cs[4] = {0.f, 0.f, 0.f, 0.f};
    #pragma unroll
    for (int half = 0; half < 2; ++half) {
        if (wr == half) {
            #pragma unroll
            for (int m = 0; m < 4; ++m)
                #pragma unroll
                for (int n = 0; n < 4; ++n)
                    #pragma unroll
                    for (int r = 0; r < 4; ++r) {
                        float e = __expf(acc[m][n][r]);
                        Es[(m*16 + r0 + r) * 136 + wc*64 + n*16 + cn] = f2b(e);
                        cs[n] += e;
                    }
        }
        __syncthreads();
        #pragma unroll
        for (int it = 0; it < 4; ++it) {
            const int idx = it * 256 + tid;
            const int rL = idx >> 4;           // 0..63
            const int cq = idx & 15;           // 16B chunk within row
            const int4 v = *(const int4*)(Es + rL * 136 + cq * 8);
            *(int4*)(Ep + (size_t)(i0 + half*64 + rL) * NN_ + j0 + cq * 8) = v;
        }
        __syncthreads();
    }
    #pragma unroll
    for (int n = 0; n < 4; ++n) {
        float s = cs[n];
        s += __shfl_xor(s, 16);
        s += __shfl_xor(s, 32);
        if (lane < 16)
            atomicAdd(&colsum[b * NN_ + j0 + wc*64 + n*16 + cn], s);
    }
}

// ---- rhs_c half-partials (z=2) via MFMA: C[m,ft] = sum_n Awt^T[m,n] * xT[ft,n] ----
#define AWS 40   // LDS row stride in ushorts (80B: 16B-aligned rows, 2-way-max bank alias)
__global__ __launch_bounds__(256) void k_rhsc(
    const unsigned short* __restrict__ chebb, const unsigned short* __restrict__ expS,
    const float* __restrict__ colsum, const float* __restrict__ x,
    float* __restrict__ rhsc)
{
    __shared__ __align__(16) unsigned short awt[3][64][AWS];  // Awt^T tiles: [k][m][n], 15 KB
    __shared__ __align__(16) unsigned short xts[48][AWS];     // x^T tile: [ft][n], rows 36..47 zero
    const int m0 = blockIdx.x * 64;
    const int b  = blockIdx.y;
    const int z  = blockIdx.z;
    const int nbase = z * 512;
    const int tid = threadIdx.x;
    const int w = tid >> 6, lane = tid & 63;
    // staging mapping: thread owns (n = sn, sn+16) x (m cols sm4..sm4+3)
    const int sn  = tid >> 4;
    const int sm4 = (tid & 15) * 4;
    float rcs4[4];
    {
        float4 rv = *(const float4*)(colsum + b * NN_ + m0 + sm4);
        rcs4[0] = 1.f / rv.x; rcs4[1] = 1.f / rv.y;
        rcs4[2] = 1.f / rv.z; rcs4[3] = 1.f / rv.w;
    }
    // zero xts pad rows 36..47 (written once; visible after first barrier)
    for (int i = tid; i < 12 * AWS; i += 256) xts[36 + i / AWS][i % AWS] = 0;

    const int fr  = lane & 15;          // frag row (m or ft within tile)
    const int kb8 = (lane >> 4) * 8;    // frag k-chunk (n within step)

    f32x4 acc[3][3];
    const f32x4 z4 = {0.f, 0.f, 0.f, 0.f};
    #pragma unroll
    for (int k = 0; k < 3; ++k)
        #pragma unroll
        for (int t = 0; t < 3; ++t) acc[k][t] = z4;

    const unsigned short* sb = expS + (size_t)b * NN_ * NN_;
    const float* xb = x + (size_t)b * NN_ * 36;

    for (int s = 0; s < 16; ++s) {
        const int n0 = nbase + s * 32;
        // ---- stage Awt^T: read expS/chebb rows coalesced, transpose-write bf16 ----
        #pragma unroll
        for (int sl = 0; sl < 2; ++sl) {
            const int n = sn + sl * 16;
            const size_t r = (size_t)(n0 + n) * NN_ + m0 + sm4;
            ushort4 pe = *(const ushort4*)(sb + r);
            const float e0 = b2f(pe.x) * rcs4[0], e1 = b2f(pe.y) * rcs4[1];
            const float e2 = b2f(pe.z) * rcs4[2], e3 = b2f(pe.w) * rcs4[3];
            #pragma unroll
            for (int k = 0; k < 3; ++k) {
                ushort4 pc = *(const ushort4*)(chebb + (size_t)k * NN_ * NN_ + r);
                awt[k][sm4 + 0][n] = f2b(b2f(pc.x) * e0);
                awt[k][sm4 + 1][n] = f2b(b2f(pc.y) * e1);
                awt[k][sm4 + 2][n] = f2b(b2f(pc.z) * e2);
                awt[k][sm4 + 3][n] = f2b(b2f(pc.w) * e3);
            }
        }
        // ---- stage x^T: 288 float4 chunks (32 n x 9 quads) ----
        #pragma unroll
        for (int j = 0; j < 2; ++j) {
            const int c2 = tid + 256 * j;
            if (c2 < 288) {
                const int n2 = c2 / 9, fq = c2 - n2 * 9;
                float4 xv = *(const float4*)(xb + (size_t)(n0 + n2) * 36 + fq * 4);
                xts[fq * 4 + 0][n2] = f2b(xv.x);
                xts[fq * 4 + 1][n2] = f2b(xv.y);
                xts[fq * 4 + 2][n2] = f2b(xv.z);
                xts[fq * 4 + 3][n2] = f2b(xv.w);
            }
        }
        __syncthreads();
        // ---- compute: wave w owns m-tile w*16; 3 k x 3 ft-tiles ----
        bf16x8 aF[3], bF[3];
        #pragma unroll
        for (int k = 0; k < 3; ++k)
            aF[k] = *(const bf16x8*)(&awt[k][w * 16 + fr][kb8]);
        #pragma unroll
        for (int t = 0; t < 3; ++t)
            bF[t] = *(const bf16x8*)(&xts[t * 16 + fr][kb8]);
        #pragma unroll
        for (int k = 0; k < 3; ++k)
            #pragma unroll
            for (int t = 0; t < 3; ++t)
                acc[k][t] = __builtin_amdgcn_mfma_f32_16x16x32_bf16(aF[k], bF[t], acc[k][t], 0, 0, 0);
        __syncthreads();
    }

    // ---- epilogue: scatter f32 partials (same layout as before; y7 unchanged) ----
    float* outb = rhsc + (size_t)z * RHSC_SZ;
    const int orow = (lane >> 4) * 4;
    #pragma unroll
    for (int k = 0; k < 3; ++k) {
        const size_t rowbase = (size_t)(b * 3 + k) * NN_ + m0 + w * 16 + orow;
        #pragma unroll
        for (int t = 0; t < 3; ++t) {
            const int col = t * 16 + fr;
            if (col < 36) {
                #pragma unroll
                for (int r = 0; r < 4; ++r)
                    outb[(rowbase + r) * 36 + col] = acc[k][t][r];
            }
        }
    }
}

// ---- fused gcn + tconv (3 shifted GEMMs, transposed out[c][nt]) + residual + relu ----
#define G2S 72
#define RSTR 112
__global__ __launch_bounds__(256) void k_y7(
    const float* __restrict__ rhsc,
    const unsigned short* __restrict__ WtG,
    const float* __restrict__ Theta, const float* __restrict__ x,
    const float* __restrict__ tcb,
    const float* __restrict__ rcw, const float* __restrict__ rcb,
    float* __restrict__ y, float* __restrict__ partials)
{
    __shared__ unsigned short Gs2[193 * G2S];
    __shared__ float Rs[16 * RSTR];
    __shared__ float xls[16 * 36];
    __shared__ float red[8];
    const int tid = threadIdx.x;
    const int wid = tid >> 6, lane = tid & 63;
    const int blk = blockIdx.x;

    const int bb = (blk * 16) >> 10;
    const int nb = (blk * 16) & 1023;
    for (int idx = tid; idx < 432; idx += 256) {
        const int i = idx / 27;
        const int r = idx - i * 27;
        const int k = r / 9;
        const int q = r - k * 9;
        const size_t off = (((size_t)bb * 3 + k) * NN_ + nb + i) * 36 + q * 4;
        float4 a = *(const float4*)(rhsc + off);
        float4 b = *(const float4*)(rhsc + RHSC_SZ + off);
        a.x += b.x; a.y += b.y; a.z += b.z; a.w += b.w;
        *(float4*)&Rs[i * RSTR + k * 36 + q * 4] = a;
    }
    if (tid < 36) ((unsigned int*)(Gs2 + 192 * G2S))[tid] = 0u;
    if (tid < 144)
        ((float4*)xls)[tid] = ((const float4*)(x + (size_t)blk * 16 * 36))[tid];
    __syncthreads();

    {
        float th[9];
        #pragma unroll
        for (int j = 0; j < 9; ++j) th[j] = Theta[j * 64 + lane];
        #pragma unroll
        for (int ii = 0; ii < 4; ++ii) {
            const int i = wid * 4 + ii;
            float g[12];
            #pragma unroll
            for (int t = 0; t < 12; ++t) g[t] = 0.f;
            #pragma unroll
            for (int kf = 0; kf < 9; ++kf) {
                const float* rp = Rs + i * RSTR + kf * 12;
                float4 v0 = *(const float4*)(rp);
                float4 v1 = *(const float4*)(rp + 4);
                float4 v2 = *(const float4*)(rp + 8);
                const float w = th[kf];
                g[0] += v0.x*w; g[1] += v0.y*w; g[2]  += v0.z*w; g[3]  += v0.w*w;
                g[4] += v1.x*w; g[5] += v1.y*w; g[6]  += v1.z*w; g[7]  += v1.w*w;
                g[8] += v2.x*w; g[9] += v2.y*w; g[10] += v2.z*w; g[11] += v2.w*w;
            }
            #pragma unroll
            for (int t = 0; t < 12; ++t)
                Gs2[(i*12 + t) * G2S + lane] = f2b(fmaxf(g[t], 0.f));
        }
    }
    __syncthreads();

    const int cl = lane & 15, kg = lane >> 4;
    bf16x8 aW[3][2];
    #pragma unroll
    for (int d = 0; d < 3; ++d)
        #pragma unroll
        for (int kb = 0; kb < 2; ++kb)
            aW[d][kb] = *(const bf16x8*)(WtG + (d*64 + wid*16 + cl) * 64 + kb*32 + kg*8);
    float tb[4], rb[4], rw0[4], rw1[4], rw2[4];
    #pragma unroll
    for (int r = 0; r < 4; ++r) {
        const int c = wid*16 + kg*4 + r;
        tb[r] = tcb[c]; rb[r] = rcb[c];
        rw0[r] = rcw[c*3]; rw1[r] = rcw[c*3+1]; rw2[r] = rcw[c*3+2];
    }
    float ls = 0.f, lss = 0.f;
    #pragma unroll
    for (int ct = 0; ct < 12; ++ct) {
        const int nt = ct * 16 + cl;
        const int i = nt / 12;
        const int t = nt - i * 12;
        const unsigned short* g1 = Gs2 + nt * G2S + kg * 8;
        const unsigned short* g0 = (t == 0)  ? (Gs2 + 192 * G2S + kg * 8) : (g1 - G2S);
        const unsigned short* g2 = (t == 11) ? (Gs2 + 192 * G2S + kg * 8) : (g1 + G2S);
        f32x4 a4 = {0.f, 0.f, 0.f, 0.f};
        #pragma unroll
        for (int kb = 0; kb < 2; ++kb) {
            a4 = __builtin_amdgcn_mfma_f32_16x16x32_bf16(aW[0][kb], *(const bf16x8*)(g0 + kb*32), a4, 0, 0, 0);
            a4 = __builtin_amdgcn_mfma_f32_16x16x32_bf16(aW[1][kb], *(const bf16x8*)(g1 + kb*32), a4, 0, 0, 0);
            a4 = __builtin_amdgcn_mfma_f32_16x16x32_bf16(aW[2][kb], *(const bf16x8*)(g2 + kb*32), a4, 0, 0, 0);
        }
        const float x0 = xls[i*36 + t];
        const float x1 = xls[i*36 + 12 + t];
        const float x2 = xls[i*36 + 24 + t];
        float* yp = y + (size_t)(blk*16 + i) * 768 + (wid*16 + kg*4) * 12 + t;
        #pragma unroll
        for (int r = 0; r < 4; ++r) {
            const float xres = rb[r] + x0*rw0[r] + x1*rw1[r] + x2*rw2[r];
            const float v = fmaxf(xres + a4[r] + tb[r], 0.f);
            ls += v; lss += v * v;
            yp[r * 12] = v;
        }
    }
    ls  = wave_reduce_sum(ls);
    lss = wave_reduce_sum(lss);
    if (lane == 0) { red[wid] = ls; red[4 + wid] = lss; }
    __syncthreads();
    if (tid == 0) {
        partials[blk]        = red[0] + red[1] + red[2] + red[3];
        partials[1024 + blk] = red[4] + red[5] + red[6] + red[7];
    }
}

// ---------------- reduce partials -> mean / inv_std ----------------
__global__ __launch_bounds__(256) void k_fin2(
    const float* __restrict__ partials, float* __restrict__ acc)
{
    const int tid = threadIdx.x;
    const int wid = tid >> 6, lane = tid & 63;
    float s = 0.f, ss = 0.f;
    #pragma unroll
    for (int j = tid; j < 1024; j += 256) {
        s  += partials[j];
        ss += partials[1024 + j];
    }
    s  = wave_reduce_sum(s);
    ss = wave_reduce_sum(ss);
    __shared__ float rs[4], rss[4];
    if (lane == 0) { rs[wid] = s; rss[wid] = ss; }
    __syncthreads();
    if (tid == 0) {
        const float cnt = (float)((size_t)BB * NN_ * 64 * TT);
        float tot  = rs[0] + rs[1] + rs[2] + rs[3];
        float tots = rss[0] + rss[1] + rss[2] + rss[3];
        float mu = tot / cnt;
        float var = tots / cnt - mu * mu;
        acc[2] = mu;
        acc[3] = rsqrtf(var + 1e-5f);
    }
}

// ---------------- normalize in place on d_out ----------------
__global__ __launch_bounds__(256) void k_norm(
    float* __restrict__ y, const float* __restrict__ lng,
    const float* __restrict__ lnb, const float* __restrict__ acc)
{
    const unsigned int i = blockIdx.x * 256u + threadIdx.x;
    const float mu = acc[2], inv = acc[3];
    float4 v  = ((const float4*)y)[i];
    float4 gv = ((const float4*)lng)[i];
    float4 bv = ((const float4*)lnb)[i];
    v.x = (v.x - mu) * inv * gv.x + bv.x;
    v.y = (v.y - mu) * inv * gv.y + bv.y;
    v.z = (v.z - mu) * inv * gv.z + bv.z;
    v.w = (v.w - mu) * inv * gv.w + bv.w;
    ((float4*)y)[i] = v;
}

extern "C" void kernel_launch(void* const* d_in, const int* in_sizes, int n_in,
                              void* d_out, int out_size, void* d_ws, size_t ws_size,
                              hipStream_t stream)
{
    const float* x    = (const float*)d_in[0];
    const float* U1   = (const float*)d_in[1];
    const float* U2   = (const float*)d_in[2];
    const float* U3   = (const float*)d_in[3];
    const float* be   = (const float*)d_in[4];
    const float* Ve   = (const float*)d_in[5];
    const float* W1   = (const float*)d_in[6];
    const float* W2   = (const float*)d_in[7];
    const float* W3   = (const float*)d_in[8];
    const float* bs   = (const float*)d_in[9];
    const float* Vs   = (const float*)d_in[10];
    const float* cheb = (const float*)d_in[11];
    const float* Th   = (const float*)d_in[12];
    const float* tcw  = (const float*)d_in[13];
    const float* tcb  = (const float*)d_in[14];
    const float* rcw  = (const float*)d_in[15];
    const float* rcb  = (const float*)d_in[16];
    const float* lng  = (const float*)d_in[17];
    const float* lnb  = (const float*)d_in[18];
    float* out = (float*)d_out;
    float* ws  = (float*)d_ws;

    float* acc    = ws + ACC_OFF;
    float* colsum = ws + COLSUM_OFF;
    float* tat    = ws + TAT_OFF;
    float* lhsT   = ws + LHST_OFF;
    float* rhs2   = ws + RHS2_OFF;
    unsigned short* Vsb   = (unsigned short*)(ws + VSB_OFF);
    unsigned short* sig2b = (unsigned short*)(ws + SIG2B_OFF);
    unsigned short* chebb = (unsigned short*)(ws + CHEBB_OFF);
    unsigned short* expS  = (unsigned short*)(ws + EXPS_OFF);
    float* rhsc   = ws + RHSC_OFF;
    unsigned short* WtG   = (unsigned short*)(ws + WTG_OFF);
    float* partials = ws + PART_OFF;

    k_pre<<<2098, 512, 0, stream>>>(ws, tcw, WtG, x, U1, U2, U3, be, Ve, tat,
                                    Vs, Vsb, cheb, chebb);
    k_xtat<<<(BB * NN_) / 256, 256, 0, stream>>>(x, tat, W1, W2, W3, lhsT, rhs2);
    k_sig2<<<1024, 256, 0, stream>>>(lhsT, rhs2, bs, sig2b);
    k_gemm_s_mfma<<<dim3(8, 8, 12), 256, 0, stream>>>((const short*)sig2b, (const short*)Vsb, expS, colsum, 0);
    k_gemm_s_mfma<<<dim3(8, 8, 4), 256, 0, stream>>>((const short*)sig2b, (const short*)Vsb, expS, colsum, 12);
    k_rhsc<<<dim3(16, BB, 2), 256, 0, stream>>>(chebb, expS, colsum, x, rhsc);
    k_y7<<<(BB * NN_) / 16, 256, 0, stream>>>(rhsc, WtG, Th, x, tcb, rcw, rcb, out, partials);
    k_fin2<<<1, 256, 0, stream>>>(partials, acc);
    k_norm<<<(BB * NN_ * 64 * TT) / 4 / 256, 256, 0, stream>>>(out, lng, lnb, acc);
}

// Round 18
// 333.804 us; speedup vs baseline: 1.0569x; 1.0569x over previous
//
#include <hip/hip_runtime.h>
#include <hip/hip_bf16.h>
#include <math.h>

#define BB 16
#define NN_ 1024
#define TT 12

typedef __attribute__((ext_vector_type(8))) short bf16x8;
typedef __attribute__((ext_vector_type(4))) float f32x4;

// ---------------- workspace layout (float units) ----------------
static const size_t ACC_OFF    = 0;          // 16
static const size_t COLSUM_OFF = 16;         // B*N = 16384
static const size_t TAT_OFF    = 16400;      // B*T*T = 2304
static const size_t LHST_OFF   = 18704;      // B*N*T = 196608
static const size_t RHS2_OFF   = 215312;     // B*T*N = 196608
static const size_t VSB_OFF    = 411920;     // N*N bf16 = 524288 floats
static const size_t SIG2B_OFF  = 936208;     // B*N*N bf16 = 8388608 floats
static const size_t CHEBB_OFF  = 9324816;    // 3*N*N bf16 = 1572864 floats
static const size_t EXPS_OFF   = 10897680;   // B*N*N bf16 = 8388608 floats
static const size_t RHSC_OFF   = 19286288;   // 4 x B*K*N*F*T fp32 (z-partials)
static const size_t WTG_OFF    = 26364176;   // 192*64 bf16 = 6144 floats
static const size_t PART_OFF   = 26370320;   // 2048 floats
// total ~26372368 floats = ~105 MB

#define RHSC_SZ 1769472

__device__ __forceinline__ float wave_reduce_sum(float v) {
    #pragma unroll
    for (int off = 32; off > 0; off >>= 1) v += __shfl_down(v, off);
    return v;
}

__device__ __forceinline__ unsigned short f2b(float f) {
    __hip_bfloat16 h = __float2bfloat16(f);
    return *(unsigned short*)&h;
}
__device__ __forceinline__ float b2f(unsigned short u) {
    return __uint_as_float(((unsigned int)u) << 16);
}

// ---------------- fused prologue: init | cvtw | temporal | cvt(Vs) | cvt(cheb) ----
__global__ __launch_bounds__(512) void k_pre(
    float* __restrict__ ws,
    const float* __restrict__ tcw, unsigned short* __restrict__ WtG,
    const float* __restrict__ x, const float* __restrict__ U1,
    const float* __restrict__ U2, const float* __restrict__ U3,
    const float* __restrict__ be, const float* __restrict__ Ve,
    float* __restrict__ tat,
    const float* __restrict__ Vs, unsigned short* __restrict__ Vsb,
    const float* __restrict__ cheb, unsigned short* __restrict__ chebb)
{
    const int blk = blockIdx.x;
    const int tid = threadIdx.x;
    if (blk < 33) {
        const int i = blk * 512 + tid;
        if (i < 16400) ws[i] = 0.f;
    } else if (blk == 33) {
        for (int j = tid; j < 12288; j += 512) {
            const int row = j >> 6;
            const int cp  = j & 63;
            const int d   = row >> 6;
            const int c   = row & 63;
            WtG[j] = f2b(tcw[c * 192 + 3 * cp + d]);
        }
    } else if (blk < 50) {
        const int b = blk - 34;
        const int wid = tid >> 6, lane = tid & 63;
        float lA[36], lM[36];
        #pragma unroll
        for (int i = 0; i < 36; ++i) { lA[i] = 0.f; lM[i] = 0.f; }
        const float u30 = U3[0], u31 = U3[1], u32 = U3[2];
        for (int n = tid; n < NN_; n += 512) {
            const float* xp = x + ((size_t)b * NN_ + n) * 36;
            float xr[36];
            #pragma unroll
            for (int i = 0; i < 9; ++i) *(float4*)&xr[i*4] = *(const float4*)(xp + i*4);
            const float u1  = U1[n];
            const float u20 = U2[n], u21 = U2[NN_ + n], u22 = U2[2*NN_ + n];
            #pragma unroll
            for (int t = 0; t < 12; ++t) {
                float ru = xr[t]*u30 + xr[12+t]*u31 + xr[24+t]*u32;
                lM[t]    += u20 * ru;
                lM[12+t] += u21 * ru;
                lM[24+t] += u22 * ru;
                lA[t]    += xr[t]    * u1;
                lA[12+t] += xr[12+t] * u1;
                lA[24+t] += xr[24+t] * u1;
            }
        }
        __shared__ float pA[8][36], pM[8][36];
        __shared__ float tA[36], tM[36], sgs[144], es[144], cmax[12], csum[12];
        #pragma unroll
        for (int i = 0; i < 36; ++i) {
            float v = wave_reduce_sum(lA[i]);
            if (lane == 0) pA[wid][i] = v;
            float w = wave_reduce_sum(lM[i]);
            if (lane == 0) pM[wid][i] = w;
        }
        __syncthreads();
        if (tid < 36) {
            float s = 0.f;
            #pragma unroll
            for (int w = 0; w < 8; ++w) s += pA[w][tid];
            tA[tid] = s;
        } else if (tid < 72) {
            const int i = tid - 36;
            float s = 0.f;
            #pragma unroll
            for (int w = 0; w < 8; ++w) s += pM[w][i];
            tM[i] = s;
        }
        __syncthreads();
        if (tid < 144) {
            int t = tid / 12, u = tid % 12;
            float p = tA[t]*tM[u] + tA[12+t]*tM[12+u] + tA[24+t]*tM[24+u];
            p += be[tid];
            sgs[tid] = 1.f / (1.f + expf(-p));
        }
        __syncthreads();
        if (tid < 144) {
            int i = tid / 12, j = tid % 12;
            float e = 0.f;
            #pragma unroll
            for (int k = 0; k < 12; ++k) e += sgs[i*12 + k] * Ve[j*12 + k];
            es[tid] = e;
        }
        __syncthreads();
        if (tid < 12) {
            int j = tid;
            float m = -1e30f;
            for (int i = 0; i < 12; ++i) m = fmaxf(m, es[i*12 + j]);
            float sx = 0.f;
            for (int i = 0; i < 12; ++i) sx += expf(es[i*12 + j] - m);
            cmax[j] = m; csum[j] = sx;
        }
        __syncthreads();
        if (tid < 144) {
            int j = tid % 12;
            tat[(size_t)b*144 + tid] = expf(es[tid] - cmax[j]) / csum[j];
        }
    } else if (blk < 562) {
        const int i = (blk - 50) * 512 + tid;
        float4 v = ((const float4*)Vs)[i];
        ushort4 o;
        o.x = f2b(v.x); o.y = f2b(v.y); o.z = f2b(v.z); o.w = f2b(v.w);
        ((ushort4*)Vsb)[i] = o;
    } else {
        const int i = (blk - 562) * 512 + tid;
        float4 v = ((const float4*)cheb)[i];
        ushort4 o;
        o.x = f2b(v.x); o.y = f2b(v.y); o.z = f2b(v.z); o.w = f2b(v.w);
        ((ushort4*)chebb)[i] = o;
    }
}

// ---------------- x_tat projections -> lhsT (B,N,T), rhs2 (B,T,N) ----------------
__global__ __launch_bounds__(256) void k_xtat(
    const float* __restrict__ x, const float* __restrict__ tat,
    const float* __restrict__ W1, const float* __restrict__ W2,
    const float* __restrict__ W3,
    float* __restrict__ lhsT, float* __restrict__ rhs2)
{
    const int id = blockIdx.x * 256 + threadIdx.x;
    const int b = id >> 10, n = id & 1023;
    const float* xp = x + (size_t)id * 36;
    float xr[36];
    #pragma unroll
    for (int i = 0; i < 9; ++i) *(float4*)&xr[i*4] = *(const float4*)(xp + i*4);
    const float* tp = tat + (size_t)b * 144;
    float xt[36];
    #pragma unroll
    for (int f = 0; f < 3; ++f)
        #pragma unroll
        for (int u = 0; u < 12; ++u) {
            float s = 0.f;
            #pragma unroll
            for (int t = 0; t < 12; ++t) s += xr[f*12 + t] * tp[t*12 + u];
            xt[f*12 + u] = s;
        }
    float lA0 = 0.f, lA1 = 0.f, lA2 = 0.f;
    #pragma unroll
    for (int t = 0; t < 12; ++t) {
        float w = W1[t];
        lA0 += xt[t]*w; lA1 += xt[12+t]*w; lA2 += xt[24+t]*w;
    }
    #pragma unroll
    for (int t2 = 0; t2 < 12; ++t2)
        lhsT[(size_t)id*12 + t2] = lA0*W2[t2] + lA1*W2[12+t2] + lA2*W2[24+t2];
    const float w30 = W3[0], w31 = W3[1], w32 = W3[2];
    #pragma unroll
    for (int u = 0; u < 12; ++u)
        rhs2[((size_t)b*12 + u)*NN_ + n] = xt[u]*w30 + xt[12+u]*w31 + xt[24+u]*w32;
}

// ---------------- sig2 (B,N,N) -> bf16, rhs2-in-registers ----------------
__global__ __launch_bounds__(256) void k_sig2(
    const float* __restrict__ lhsT, const float* __restrict__ rhs2,
    const float* __restrict__ bs, unsigned short* __restrict__ sig2b)
{
    const int nt = blockIdx.x & 63;       // n-tile (16 rows)
    const int mt = blockIdx.x >> 6;       // m-tile (64 cols)
    const int mq = threadIdx.x & 15;
    const int b  = threadIdx.x >> 4;
    const int m4 = mt * 64 + mq * 4;
    const int n0 = nt * 16;
    float4 r[12];
    #pragma unroll
    for (int t = 0; t < 12; ++t)
        r[t] = *(const float4*)(rhs2 + ((size_t)b * 12 + t) * NN_ + m4);
    const float* lb = lhsT + ((size_t)b * NN_ + n0) * 12;
    #pragma unroll 4
    for (int ni = 0; ni < 16; ++ni) {
        const float* lp = lb + ni * 12;
        float l[12];
        *(float4*)&l[0] = *(const float4*)(lp);
        *(float4*)&l[4] = *(const float4*)(lp + 4);
        *(float4*)&l[8] = *(const float4*)(lp + 8);
        float4 z = *(const float4*)(bs + (size_t)(n0 + ni) * NN_ + m4);
        #pragma unroll
        for (int t = 0; t < 12; ++t) {
            z.x += l[t] * r[t].x; z.y += l[t] * r[t].y;
            z.z += l[t] * r[t].z; z.w += l[t] * r[t].w;
        }
        ushort4 o;
        o.x = f2b(1.f / (1.f + __expf(-z.x)));
        o.y = f2b(1.f / (1.f + __expf(-z.y)));
        o.z = f2b(1.f / (1.f + __expf(-z.z)));
        o.w = f2b(1.f / (1.f + __expf(-z.w)));
        *(ushort4*)(sig2b + ((size_t)b * NN_ + n0 + ni) * NN_ + m4) = o;
    }
}

// ---------------- S = sig2 @ Vs^T, fused exp + colsum; store expS bf16 ----------------
// 2-phase K-loop, 128x128 tile. gridDim.z-parametric bijective XCD swizzle.
__global__ __launch_bounds__(256) void k_gemm_s_mfma(
    const short* __restrict__ A, const short* __restrict__ Bm,
    unsigned short* __restrict__ E, float* __restrict__ colsum, int boff)
{
    __shared__ __align__(16) short smemU[16384];   // 32 KB: two 16 KB buffers
    const int lid = blockIdx.x + 8 * (blockIdx.y + 8 * blockIdx.z);
    const int tile = (lid & 7) * (8 * (int)gridDim.z) + (lid >> 3);
    const int j0 = (tile & 7) * 128;
    const int i0 = ((tile >> 3) & 7) * 128;
    const int b  = boff + (tile >> 6);
    const int tid = threadIdx.x;
    const int wid = tid >> 6;
    const int lane = tid & 63;
    const int wr = wid & 1, wc = wid >> 1;
    const short* Ab = A + (size_t)b * NN_ * NN_;

    f32x4 acc[4][4];
    const f32x4 z4 = {0.f, 0.f, 0.f, 0.f};
    #pragma unroll
    for (int m = 0; m < 4; ++m)
        #pragma unroll
        for (int n = 0; n < 4; ++n) acc[m][n] = z4;

    const int srow = lane >> 2;
    const int schk = lane & 3;
    const int fr = lane & 15;
    const int kb = (lane >> 4) * 8;

    auto STAGE = [&](int bufofs, int k0) {
        #pragma unroll
        for (int q = 0; q < 2; ++q) {
            const int rb = (wid * 2 + q) * 16;
            const short* srcA = Ab + (size_t)(i0 + rb + srow) * NN_ + k0 + schk * 8;
            const short* srcB = Bm + (size_t)(j0 + rb + srow) * NN_ + k0 + schk * 8;
            __builtin_amdgcn_global_load_lds(
                (const __attribute__((address_space(1))) unsigned int*)srcA,
                (__attribute__((address_space(3))) unsigned int*)(smemU + bufofs + rb * 32), 16, 0, 0);
            __builtin_amdgcn_global_load_lds(
                (const __attribute__((address_space(1))) unsigned int*)srcB,
                (__attribute__((address_space(3))) unsigned int*)(smemU + bufofs + 4096 + rb * 32), 16, 0, 0);
        }
    };

    STAGE(0, 0);
    __syncthreads();

    int cur = 0;
    for (int k0 = 0; k0 < NN_; k0 += 32) {
        if (k0 + 32 < NN_) STAGE((cur ^ 1) * 8192, k0 + 32);
        const short* As = smemU + cur * 8192;
        const short* Bs = smemU + cur * 8192 + 4096;
        bf16x8 aF[4], bF[4];
        #pragma unroll
        for (int m = 0; m < 4; ++m)
            aF[m] = *(const bf16x8*)(As + (wr*64 + m*16 + fr) * 32 + kb);
        #pragma unroll
        for (int n = 0; n < 4; ++n)
            bF[n] = *(const bf16x8*)(Bs + (wc*64 + n*16 + fr) * 32 + kb);
        __builtin_amdgcn_s_setprio(1);
        #pragma unroll
        for (int m = 0; m < 4; ++m)
            #pragma unroll
            for (int n = 0; n < 4; ++n)
                acc[m][n] = __builtin_amdgcn_mfma_f32_16x16x32_bf16(aF[m], bF[n], acc[m][n], 0, 0, 0);
        __builtin_amdgcn_s_setprio(0);
        __syncthreads();
        cur ^= 1;
    }
    // ---- epilogue: exp(acc) -> LDS (bf16, aliases buffers) -> dwordx4 flush ----
    unsigned short* Es = (unsigned short*)smemU;   // rows of stride 136 ushorts
    unsigned short* Ep = E + (size_t)b * NN_ * NN_;
    const int cn = lane & 15;
    const int r0 = (lane >> 4) * 4;
    float cs[4] = {0.f, 0.f, 0.f, 0.f};
    #pragma unroll
    for (int half = 0; half < 2; ++half) {
        if (wr == half) {
            #pragma unroll
            for (int m = 0; m < 4; ++m)
                #pragma unroll
                for (int n = 0; n < 4; ++n)
                    #pragma unroll
                    for (int r = 0; r < 4; ++r) {
                        float e = __expf(acc[m][n][r]);
                        Es[(m*16 + r0 + r) * 136 + wc*64 + n*16 + cn] = f2b(e);
                        cs[n] += e;
                    }
        }
        __syncthreads();
        #pragma unroll
        for (int it = 0; it < 4; ++it) {
            const int idx = it * 256 + tid;
            const int rL = idx >> 4;
            const int cq = idx & 15;
            const int4 v = *(const int4*)(Es + rL * 136 + cq * 8);
            *(int4*)(Ep + (size_t)(i0 + half*64 + rL) * NN_ + j0 + cq * 8) = v;
        }
        __syncthreads();
    }
    #pragma unroll
    for (int n = 0; n < 4; ++n) {
        float s = cs[n];
        s += __shfl_xor(s, 16);
        s += __shfl_xor(s, 32);
        if (lane < 16)
            atomicAdd(&colsum[b * NN_ + j0 + wc*64 + n*16 + cn], s);
    }
}

// ---- rhs_c quarter-partials (z=4) via MFMA (proven simple stage/compute loop) ----
// z=4: 1024 blocks = 4/CU for TLP (R16: z=2 was latency-bound, 17% occupancy).
// NO prefetch split — R17's ISSUE/WRITE split diverged on replay (suspected race).
#define AWS 40   // LDS row stride in ushorts (80B: 16B-aligned rows)
__global__ __launch_bounds__(256) void k_rhsc(
    const unsigned short* __restrict__ chebb, const unsigned short* __restrict__ expS,
    const float* __restrict__ colsum, const float* __restrict__ x,
    float* __restrict__ rhsc)
{
    __shared__ __align__(16) unsigned short awt[3][64][AWS];  // Awt^T tiles: [k][m][n]
    __shared__ __align__(16) unsigned short xts[48][AWS];     // x^T tile: [ft][n]
    const int m0 = blockIdx.x * 64;
    const int b  = blockIdx.y;
    const int z  = blockIdx.z;
    const int nbase = z * 256;
    const int tid = threadIdx.x;
    const int w = tid >> 6, lane = tid & 63;
    const int sn  = tid >> 4;
    const int sm4 = (tid & 15) * 4;
    float rcs4[4];
    {
        float4 rv = *(const float4*)(colsum + b * NN_ + m0 + sm4);
        rcs4[0] = 1.f / rv.x; rcs4[1] = 1.f / rv.y;
        rcs4[2] = 1.f / rv.z; rcs4[3] = 1.f / rv.w;
    }
    // zero xts pad rows 36..47 (written once; visible after first barrier)
    for (int i = tid; i < 12 * AWS; i += 256) xts[36 + i / AWS][i % AWS] = 0;

    const int fr  = lane & 15;
    const int kb8 = (lane >> 4) * 8;

    f32x4 acc[3][3];
    const f32x4 z4 = {0.f, 0.f, 0.f, 0.f};
    #pragma unroll
    for (int k = 0; k < 3; ++k)
        #pragma unroll
        for (int t = 0; t < 3; ++t) acc[k][t] = z4;

    const unsigned short* sb = expS + (size_t)b * NN_ * NN_;
    const float* xb = x + (size_t)b * NN_ * 36;

    for (int s = 0; s < 8; ++s) {
        const int n0 = nbase + s * 32;
        // ---- stage Awt^T: read expS/chebb rows coalesced, transpose-write bf16 ----
        #pragma unroll
        for (int sl = 0; sl < 2; ++sl) {
            const int n = sn + sl * 16;
            const size_t r = (size_t)(n0 + n) * NN_ + m0 + sm4;
            ushort4 pe = *(const ushort4*)(sb + r);
            const float e0 = b2f(pe.x) * rcs4[0], e1 = b2f(pe.y) * rcs4[1];
            const float e2 = b2f(pe.z) * rcs4[2], e3 = b2f(pe.w) * rcs4[3];
            #pragma unroll
            for (int k = 0; k < 3; ++k) {
                ushort4 pc = *(const ushort4*)(chebb + (size_t)k * NN_ * NN_ + r);
                awt[k][sm4 + 0][n] = f2b(b2f(pc.x) * e0);
                awt[k][sm4 + 1][n] = f2b(b2f(pc.y) * e1);
                awt[k][sm4 + 2][n] = f2b(b2f(pc.z) * e2);
                awt[k][sm4 + 3][n] = f2b(b2f(pc.w) * e3);
            }
        }
        // ---- stage x^T: 288 float4 chunks (32 n x 9 quads) ----
        #pragma unroll
        for (int j = 0; j < 2; ++j) {
            const int c2 = tid + 256 * j;
            if (c2 < 288) {
                const int n2 = c2 / 9, fq = c2 - n2 * 9;
                float4 xv = *(const float4*)(xb + (size_t)(n0 + n2) * 36 + fq * 4);
                xts[fq * 4 + 0][n2] = f2b(xv.x);
                xts[fq * 4 + 1][n2] = f2b(xv.y);
                xts[fq * 4 + 2][n2] = f2b(xv.z);
                xts[fq * 4 + 3][n2] = f2b(xv.w);
            }
        }
        __syncthreads();
        // ---- compute: wave w owns m-tile w*16; 3 k x 3 ft-tiles ----
        bf16x8 aF[3], bF[3];
        #pragma unroll
        for (int k = 0; k < 3; ++k)
            aF[k] = *(const bf16x8*)(&awt[k][w * 16 + fr][kb8]);
        #pragma unroll
        for (int t = 0; t < 3; ++t)
            bF[t] = *(const bf16x8*)(&xts[t * 16 + fr][kb8]);
        #pragma unroll
        for (int k = 0; k < 3; ++k)
            #pragma unroll
            for (int t = 0; t < 3; ++t)
                acc[k][t] = __builtin_amdgcn_mfma_f32_16x16x32_bf16(aF[k], bF[t], acc[k][t], 0, 0, 0);
        __syncthreads();
    }

    // ---- epilogue: scatter f32 partials (z in 0..3) ----
    float* outb = rhsc + (size_t)z * RHSC_SZ;
    const int orow = (lane >> 4) * 4;
    #pragma unroll
    for (int k = 0; k < 3; ++k) {
        const size_t rowbase = (size_t)(b * 3 + k) * NN_ + m0 + w * 16 + orow;
        #pragma unroll
        for (int t = 0; t < 3; ++t) {
            const int col = t * 16 + fr;
            if (col < 36) {
                #pragma unroll
                for (int r = 0; r < 4; ++r)
                    outb[(rowbase + r) * 36 + col] = acc[k][t][r];
            }
        }
    }
}

// ---- fused gcn + tconv (3 shifted GEMMs) + residual + relu; sums 4 z-partials ----
#define G2S 72
#define RSTR 112
__global__ __launch_bounds__(256) void k_y7(
    const float* __restrict__ rhsc,
    const unsigned short* __restrict__ WtG,
    const float* __restrict__ Theta, const float* __restrict__ x,
    const float* __restrict__ tcb,
    const float* __restrict__ rcw, const float* __restrict__ rcb,
    float* __restrict__ y, float* __restrict__ partials)
{
    __shared__ unsigned short Gs2[193 * G2S];
    __shared__ float Rs[16 * RSTR];
    __shared__ float xls[16 * 36];
    __shared__ float red[8];
    const int tid = threadIdx.x;
    const int wid = tid >> 6, lane = tid & 63;
    const int blk = blockIdx.x;

    const int bb = (blk * 16) >> 10;
    const int nb = (blk * 16) & 1023;
    for (int idx = tid; idx < 432; idx += 256) {
        const int i = idx / 27;
        const int r = idx - i * 27;
        const int k = r / 9;
        const int q = r - k * 9;
        const size_t off = (((size_t)bb * 3 + k) * NN_ + nb + i) * 36 + q * 4;
        float4 a = *(const float4*)(rhsc + off);
        float4 b = *(const float4*)(rhsc + RHSC_SZ + off);
        float4 c = *(const float4*)(rhsc + 2 * RHSC_SZ + off);
        float4 d = *(const float4*)(rhsc + 3 * RHSC_SZ + off);
        a.x += b.x + c.x + d.x; a.y += b.y + c.y + d.y;
        a.z += b.z + c.z + d.z; a.w += b.w + c.w + d.w;
        *(float4*)&Rs[i * RSTR + k * 36 + q * 4] = a;
    }
    if (tid < 36) ((unsigned int*)(Gs2 + 192 * G2S))[tid] = 0u;
    if (tid < 144)
        ((float4*)xls)[tid] = ((const float4*)(x + (size_t)blk * 16 * 36))[tid];
    __syncthreads();

    {
        float th[9];
        #pragma unroll
        for (int j = 0; j < 9; ++j) th[j] = Theta[j * 64 + lane];
        #pragma unroll
        for (int ii = 0; ii < 4; ++ii) {
            const int i = wid * 4 + ii;
            float g[12];
            #pragma unroll
            for (int t = 0; t < 12; ++t) g[t] = 0.f;
            #pragma unroll
            for (int kf = 0; kf < 9; ++kf) {
                const float* rp = Rs + i * RSTR + kf * 12;
                float4 v0 = *(const float4*)(rp);
                float4 v1 = *(const float4*)(rp + 4);
                float4 v2 = *(const float4*)(rp + 8);
                const float w = th[kf];
                g[0] += v0.x*w; g[1] += v0.y*w; g[2]  += v0.z*w; g[3]  += v0.w*w;
                g[4] += v1.x*w; g[5] += v1.y*w; g[6]  += v1.z*w; g[7]  += v1.w*w;
                g[8] += v2.x*w; g[9] += v2.y*w; g[10] += v2.z*w; g[11] += v2.w*w;
            }
            #pragma unroll
            for (int t = 0; t < 12; ++t)
                Gs2[(i*12 + t) * G2S + lane] = f2b(fmaxf(g[t], 0.f));
        }
    }
    __syncthreads();

    const int cl = lane & 15, kg = lane >> 4;
    bf16x8 aW[3][2];
    #pragma unroll
    for (int d = 0; d < 3; ++d)
        #pragma unroll
        for (int kb = 0; kb < 2; ++kb)
            aW[d][kb] = *(const bf16x8*)(WtG + (d*64 + wid*16 + cl) * 64 + kb*32 + kg*8);
    float tb[4], rb[4], rw0[4], rw1[4], rw2[4];
    #pragma unroll
    for (int r = 0; r < 4; ++r) {
        const int c = wid*16 + kg*4 + r;
        tb[r] = tcb[c]; rb[r] = rcb[c];
        rw0[r] = rcw[c*3]; rw1[r] = rcw[c*3+1]; rw2[r] = rcw[c*3+2];
    }
    float ls = 0.f, lss = 0.f;
    #pragma unroll
    for (int ct = 0; ct < 12; ++ct) {
        const int nt = ct * 16 + cl;
        const int i = nt / 12;
        const int t = nt - i * 12;
        const unsigned short* g1 = Gs2 + nt * G2S + kg * 8;
        const unsigned short* g0 = (t == 0)  ? (Gs2 + 192 * G2S + kg * 8) : (g1 - G2S);
        const unsigned short* g2 = (t == 11) ? (Gs2 + 192 * G2S + kg * 8) : (g1 + G2S);
        f32x4 a4 = {0.f, 0.f, 0.f, 0.f};
        #pragma unroll
        for (int kb = 0; kb < 2; ++kb) {
            a4 = __builtin_amdgcn_mfma_f32_16x16x32_bf16(aW[0][kb], *(const bf16x8*)(g0 + kb*32), a4, 0, 0, 0);
            a4 = __builtin_amdgcn_mfma_f32_16x16x32_bf16(aW[1][kb], *(const bf16x8*)(g1 + kb*32), a4, 0, 0, 0);
            a4 = __builtin_amdgcn_mfma_f32_16x16x32_bf16(aW[2][kb], *(const bf16x8*)(g2 + kb*32), a4, 0, 0, 0);
        }
        const float x0 = xls[i*36 + t];
        const float x1 = xls[i*36 + 12 + t];
        const float x2 = xls[i*36 + 24 + t];
        float* yp = y + (size_t)(blk*16 + i) * 768 + (wid*16 + kg*4) * 12 + t;
        #pragma unroll
        for (int r = 0; r < 4; ++r) {
            const float xres = rb[r] + x0*rw0[r] + x1*rw1[r] + x2*rw2[r];
            const float v = fmaxf(xres + a4[r] + tb[r], 0.f);
            ls += v; lss += v * v;
            yp[r * 12] = v;
        }
    }
    ls  = wave_reduce_sum(ls);
    lss = wave_reduce_sum(lss);
    if (lane == 0) { red[wid] = ls; red[4 + wid] = lss; }
    __syncthreads();
    if (tid == 0) {
        partials[blk]        = red[0] + red[1] + red[2] + red[3];
        partials[1024 + blk] = red[4] + red[5] + red[6] + red[7];
    }
}

// ---------------- reduce partials -> mean / inv_std ----------------
__global__ __launch_bounds__(256) void k_fin2(
    const float* __restrict__ partials, float* __restrict__ acc)
{
    const int tid = threadIdx.x;
    const int wid = tid >> 6, lane = tid & 63;
    float s = 0.f, ss = 0.f;
    #pragma unroll
    for (int j = tid; j < 1024; j += 256) {
        s  += partials[j];
        ss += partials[1024 + j];
    }
    s  = wave_reduce_sum(s);
    ss = wave_reduce_sum(ss);
    __shared__ float rs[4], rss[4];
    if (lane == 0) { rs[wid] = s; rss[wid] = ss; }
    __syncthreads();
    if (tid == 0) {
        const float cnt = (float)((size_t)BB * NN_ * 64 * TT);
        float tot  = rs[0] + rs[1] + rs[2] + rs[3];
        float tots = rss[0] + rss[1] + rss[2] + rss[3];
        float mu = tot / cnt;
        float var = tots / cnt - mu * mu;
        acc[2] = mu;
        acc[3] = rsqrtf(var + 1e-5f);
    }
}

// ---------------- normalize in place on d_out ----------------
__global__ __launch_bounds__(256) void k_norm(
    float* __restrict__ y, const float* __restrict__ lng,
    const float* __restrict__ lnb, const float* __restrict__ acc)
{
    const unsigned int i = blockIdx.x * 256u + threadIdx.x;
    const float mu = acc[2], inv = acc[3];
    float4 v  = ((const float4*)y)[i];
    float4 gv = ((const float4*)lng)[i];
    float4 bv = ((const float4*)lnb)[i];
    v.x = (v.x - mu) * inv * gv.x + bv.x;
    v.y = (v.y - mu) * inv * gv.y + bv.y;
    v.z = (v.z - mu) * inv * gv.z + bv.z;
    v.w = (v.w - mu) * inv * gv.w + bv.w;
    ((float4*)y)[i] = v;
}

extern "C" void kernel_launch(void* const* d_in, const int* in_sizes, int n_in,
                              void* d_out, int out_size, void* d_ws, size_t ws_size,
                              hipStream_t stream)
{
    const float* x    = (const float*)d_in[0];
    const float* U1   = (const float*)d_in[1];
    const float* U2   = (const float*)d_in[2];
    const float* U3   = (const float*)d_in[3];
    const float* be   = (const float*)d_in[4];
    const float* Ve   = (const float*)d_in[5];
    const float* W1   = (const float*)d_in[6];
    const float* W2   = (const float*)d_in[7];
    const float* W3   = (const float*)d_in[8];
    const float* bs   = (const float*)d_in[9];
    const float* Vs   = (const float*)d_in[10];
    const float* cheb = (const float*)d_in[11];
    const float* Th   = (const float*)d_in[12];
    const float* tcw  = (const float*)d_in[13];
    const float* tcb  = (const float*)d_in[14];
    const float* rcw  = (const float*)d_in[15];
    const float* rcb  = (const float*)d_in[16];
    const float* lng  = (const float*)d_in[17];
    const float* lnb  = (const float*)d_in[18];
    float* out = (float*)d_out;
    float* ws  = (float*)d_ws;

    float* acc    = ws + ACC_OFF;
    float* colsum = ws + COLSUM_OFF;
    float* tat    = ws + TAT_OFF;
    float* lhsT   = ws + LHST_OFF;
    float* rhs2   = ws + RHS2_OFF;
    unsigned short* Vsb   = (unsigned short*)(ws + VSB_OFF);
    unsigned short* sig2b = (unsigned short*)(ws + SIG2B_OFF);
    unsigned short* chebb = (unsigned short*)(ws + CHEBB_OFF);
    unsigned short* expS  = (unsigned short*)(ws + EXPS_OFF);
    float* rhsc   = ws + RHSC_OFF;
    unsigned short* WtG   = (unsigned short*)(ws + WTG_OFF);
    float* partials = ws + PART_OFF;

    k_pre<<<2098, 512, 0, stream>>>(ws, tcw, WtG, x, U1, U2, U3, be, Ve, tat,
                                    Vs, Vsb, cheb, chebb);
    k_xtat<<<(BB * NN_) / 256, 256, 0, stream>>>(x, tat, W1, W2, W3, lhsT, rhs2);
    k_sig2<<<1024, 256, 0, stream>>>(lhsT, rhs2, bs, sig2b);
    k_gemm_s_mfma<<<dim3(8, 8, BB), 256, 0, stream>>>((const short*)sig2b, (const short*)Vsb, expS, colsum, 0);
    k_rhsc<<<dim3(16, BB, 4), 256, 0, stream>>>(chebb, expS, colsum, x, rhsc);
    k_y7<<<(BB * NN_) / 16, 256, 0, stream>>>(rhsc, WtG, Th, x, tcb, rcw, rcb, out, partials);
    k_fin2<<<1, 256, 0, stream>>>(partials, acc);
    k_norm<<<(BB * NN_ * 64 * TT) / 4 / 256, 256, 0, stream>>>(out, lng, lnb, acc);
}